// Round 1
// 585.474 us; speedup vs baseline: 1.0794x; 1.0794x over previous
//
#include <hip/hip_runtime.h>
#include <stdint.h>

#define N_NODES 10000
#define N_EDGES 320000
#define F_IN 512
#define F_OUT 64

typedef __attribute__((ext_vector_type(8)))  __bf16 bf16x8;
typedef __attribute__((ext_vector_type(8)))  short  short8;
typedef __attribute__((ext_vector_type(16))) float  f32x16;
typedef __attribute__((ext_vector_type(4)))  float  float4v;

// ---- scratch layout inside d_out's adj region (float element offsets) ----
#define OFF_H1P    0          // 640,000 f
#define OFF_H1     640000     // 640,000 f (unused after k4+k5 fusion)
#define OFF_MUP    1280000    // 640,000 f
#define OFF_STDP   1920000    // 640,000 f
#define OFF_DEGIN  2560000    // 10,000 int
#define OFF_DEGOUT 2570000    // 10,000 int
#define OFF_OFFS   2580000    // 10,001 int
#define OFF_CURS   2592000    // 10,000 int
#define OFF_SCIN   2604000    // 10,000 f
#define OFF_SCOUT  2616000    // 10,000 f
#define OFF_CSR    2628000    // 320,000 int
#define OFF_WBUF   2948000    // 32,768 ushort (16,384 f), 16B-aligned

__device__ __forceinline__ unsigned short f2bf(float f) {
    unsigned u = __builtin_bit_cast(unsigned, f);
    u += 0x7fffu + ((u >> 16) & 1u);   // round-to-nearest-even
    return (unsigned short)(u >> 16);
}
__device__ __forceinline__ float bf2f(unsigned short h) {
    unsigned u = ((unsigned)h) << 16;
    return __builtin_bit_cast(float, u);
}
__device__ __forceinline__ f32x16 zero16() {
    f32x16 v;
#pragma unroll
    for (int i = 0; i < 16; ++i) v[i] = 0.f;
    return v;
}

// K0: integer degrees via atomics + swizzle W1 into MFMA B-fragment-linear bf16
__global__ void k0_deg_wswz(const int* __restrict__ src, const int* __restrict__ dst,
                            const float* __restrict__ W1,
                            int* __restrict__ deg_out, int* __restrict__ deg_in,
                            unsigned short* __restrict__ wbuf) {
    int bid = blockIdx.x, tid = threadIdx.x;
    if (bid < 1250) {
        int e = bid * 256 + tid;
        if (e < N_EDGES) {
            atomicAdd(&deg_out[src[e]], 1);
            atomicAdd(&deg_in[dst[e]], 1);
        }
    } else {
        int q = (bid - 1250) * 256 + tid;   // 2*32*64*8 = 32768 exactly
        int j = q & 7, l = (q >> 3) & 63, c = (q >> 9) & 31, t = q >> 14;
        int k = c * 16 + ((l >> 5) << 3) + j;        // B frag: k = c*16 + half*8 + j
        int n = (t << 5) + (l & 31);                 // n = tile*32 + (lane&31)
        wbuf[q] = f2bf(W1[k * F_OUT + n]);
    }
}

// K1: single-block exclusive scan of deg_in -> CSR offsets + cursors + rsqrt scales
__global__ void __launch_bounds__(1024) k1_scan(const int* __restrict__ deg_in,
                                                const int* __restrict__ deg_out,
                                                int* __restrict__ offs, int* __restrict__ curs,
                                                float* __restrict__ sc_in, float* __restrict__ sc_out) {
    __shared__ int sdata[1024];
    int t = threadIdx.x;
    int loc[10];
    int s = 0;
#pragma unroll
    for (int u = 0; u < 10; ++u) {
        int idx = t * 10 + u;
        int v = (idx < N_NODES) ? deg_in[idx] : 0;
        loc[u] = v; s += v;
    }
    sdata[t] = s;
    __syncthreads();
    for (int off = 1; off < 1024; off <<= 1) {
        int v = sdata[t];
        int add = (t >= off) ? sdata[t - off] : 0;
        __syncthreads();
        sdata[t] = v + add;
        __syncthreads();
    }
    int run = (t == 0) ? 0 : sdata[t - 1];
#pragma unroll
    for (int u = 0; u < 10; ++u) {
        int idx = t * 10 + u;
        if (idx < N_NODES) {
            offs[idx] = run; curs[idx] = run;
            run += loc[u];
            sc_in[idx] = rsqrtf((float)max(loc[u], 1));
            sc_out[idx] = rsqrtf((float)max(deg_out[idx], 1));
        }
    }
    if (t == 1023) offs[N_NODES] = sdata[1023];
}

// K2: CSR fill (edge list bucketed by dst)
__global__ void k2_csr(const int* __restrict__ src, const int* __restrict__ dst,
                       int* __restrict__ curs, int* __restrict__ csr) {
    int e = blockIdx.x * 256 + threadIdx.x;
    if (e < N_EDGES) {
        int d = dst[e];
        int p = atomicAdd(&curs[d], 1);
        csr[p] = src[e];
    }
}

// K3: h1p = (feat @ W1) * rsqrt(deg_out)  via bf16 MFMA, split-K over 4 waves
__global__ void __launch_bounds__(256) k3_proj1(const float* __restrict__ feat,
                                                const unsigned short* __restrict__ wbuf,
                                                const float* __restrict__ sc_out,
                                                float* __restrict__ h1p) {
    __shared__ float red[4][32 * 64];  // 32 KB
    int tid = threadIdx.x;
    int wid = tid >> 6;
    int l = tid & 63;
    int half = l >> 5;
    int rowbase = blockIdx.x * 32;
    int m = rowbase + (l & 31);
    if (m > N_NODES - 1) m = N_NODES - 1;
    const float* arow = feat + (size_t)m * F_IN + half * 8;

    f32x16 acc0 = zero16(), acc1 = zero16();
    int cbeg = wid * 8;
#pragma unroll
    for (int cc = 0; cc < 8; ++cc) {
        int c = cbeg + cc;
        float4v a0 = *(const float4v*)(arow + c * 16);
        float4v a1 = *(const float4v*)(arow + c * 16 + 4);
        short8 as;
        as[0] = (short)f2bf(a0[0]); as[1] = (short)f2bf(a0[1]);
        as[2] = (short)f2bf(a0[2]); as[3] = (short)f2bf(a0[3]);
        as[4] = (short)f2bf(a1[0]); as[5] = (short)f2bf(a1[1]);
        as[6] = (short)f2bf(a1[2]); as[7] = (short)f2bf(a1[3]);
        bf16x8 af = __builtin_bit_cast(bf16x8, as);
        bf16x8 b0 = __builtin_bit_cast(bf16x8, *(const short8*)(wbuf + (size_t)((0 * 32 + c) * 64 + l) * 8));
        bf16x8 b1 = __builtin_bit_cast(bf16x8, *(const short8*)(wbuf + (size_t)((1 * 32 + c) * 64 + l) * 8));
        acc0 = __builtin_amdgcn_mfma_f32_32x32x16_bf16(af, b0, acc0, 0, 0, 0);
        acc1 = __builtin_amdgcn_mfma_f32_32x32x16_bf16(af, b1, acc1, 0, 0, 0);
    }
#pragma unroll
    for (int r = 0; r < 16; ++r) {
        int row = (r & 3) + 8 * (r >> 2) + 4 * half;   // 32x32 C/D layout
        int col = l & 31;
        red[wid][row * 64 + col] = acc0[r];
        red[wid][row * 64 + 32 + col] = acc1[r];
    }
    __syncthreads();
#pragma unroll
    for (int i = 0; i < 8; ++i) {
        int idx = tid * 8 + i;
        int row = idx >> 6, col = idx & 63;
        int gr = rowbase + row;
        if (gr < N_NODES) {
            float v = red[0][idx] + red[1][idx] + red[2][idx] + red[3][idx];
            h1p[gr * F_OUT + col] = v * sc_out[gr];
        }
    }
}

// K45: fused gather1 + proj2.
//   h1[n] = rsqrt(deg_in)*sum h1p[src] + b1  (in LDS, never touches HBM)
//   mup   = (h1@Wmu)*rsqrt(deg_out); stdp = (h1@Wstd)*rsqrt(deg_out)
// Gather loop unrolled x4: 4 independent csr loads then 4 independent row loads
// per round -> breaks the dependent L2-latency chain (csr[e] -> h1p[csr[e]]).
// Accumulation order is kept sequential (bitwise-identical to the unfused k4).
__global__ void __launch_bounds__(1024) k45_gather_proj(
        const int* __restrict__ offs, const int* __restrict__ csr,
        const float* __restrict__ h1p,
        const float* __restrict__ sc_in, const float* __restrict__ sc_out,
        const float* __restrict__ b1,
        const float* __restrict__ Wmu, const float* __restrict__ Wstd,
        float* __restrict__ mup, float* __restrict__ stdp) {
    __shared__ float wmuT[64 * 65];   // +1 pad: bank-conflict-free
    __shared__ float wstdT[64 * 65];
    __shared__ float hrow[16 * 64];
    int tid = threadIdx.x;
#pragma unroll
    for (int i0 = 0; i0 < 4096; i0 += 1024) {
        int i = i0 + tid;
        int k = i >> 6, o2 = i & 63;
        wmuT[o2 * 65 + k] = Wmu[i];
        wstdT[o2 * 65 + k] = Wstd[i];
    }
    int ln = tid >> 6, o = tid & 63;
    int n = blockIdx.x * 16 + ln;      // grid=625 exact
    int e0 = offs[n], e1 = offs[n + 1];
    float acc = 0.f;
    int e = e0;
    for (; e + 4 <= e1; e += 4) {
        int s0 = csr[e], s1 = csr[e + 1], s2 = csr[e + 2], s3 = csr[e + 3];
        float v0 = h1p[s0 * F_OUT + o];
        float v1 = h1p[s1 * F_OUT + o];
        float v2 = h1p[s2 * F_OUT + o];
        float v3 = h1p[s3 * F_OUT + o];
        acc += v0; acc += v1; acc += v2; acc += v3;
    }
    for (; e < e1; ++e) acc += h1p[csr[e] * F_OUT + o];
    hrow[ln * 64 + o] = acc * sc_in[n] + b1[o];
    __syncthreads();
    float amu = 0.f, asd = 0.f;
#pragma unroll
    for (int k = 0; k < 64; ++k) {
        float h = hrow[ln * 64 + k];
        amu += h * wmuT[o * 65 + k];
        asd += h * wstdT[o * 65 + k];
    }
    float s = sc_out[n];
    mup[n * F_OUT + o] = amu * s;
    stdp[n * F_OUT + o] = asd * s;
}

// K6: dual gather -> mu, logvar; std=exp(lv); z = eps*std + mu; emit z_hi/z_lo bf16 split
// Gather unrolled x4 like K45.
__global__ void __launch_bounds__(256) k6_gather2(const int* __restrict__ offs, const int* __restrict__ csr,
                                                  const float* __restrict__ mup, const float* __restrict__ stdp,
                                                  const float* __restrict__ sc_in,
                                                  const float* __restrict__ bmu, const float* __restrict__ bstd,
                                                  const float* __restrict__ eps,
                                                  float* __restrict__ out_mu, float* __restrict__ out_std,
                                                  unsigned short* __restrict__ zhi, unsigned short* __restrict__ zlo) {
    int tid = threadIdx.x;
    int n = blockIdx.x * 4 + (tid >> 6);
    int o = tid & 63;
    int e0 = offs[n], e1 = offs[n + 1];
    float amu = 0.f, alv = 0.f;
    int e = e0;
    for (; e + 4 <= e1; e += 4) {
        int s0 = csr[e], s1 = csr[e + 1], s2 = csr[e + 2], s3 = csr[e + 3];
        float m0 = mup[s0 * F_OUT + o], l0 = stdp[s0 * F_OUT + o];
        float m1 = mup[s1 * F_OUT + o], l1 = stdp[s1 * F_OUT + o];
        float m2 = mup[s2 * F_OUT + o], l2 = stdp[s2 * F_OUT + o];
        float m3 = mup[s3 * F_OUT + o], l3 = stdp[s3 * F_OUT + o];
        amu += m0; amu += m1; amu += m2; amu += m3;
        alv += l0; alv += l1; alv += l2; alv += l3;
    }
    for (; e < e1; ++e) {
        int s = csr[e];
        amu += mup[s * F_OUT + o];
        alv += stdp[s * F_OUT + o];
    }
    float si = sc_in[n];
    float mu = amu * si + bmu[o];
    float lv = alv * si + bstd[o];
    float sd = __expf(lv);
    float z = eps[n * F_OUT + o] * sd + mu;
    out_mu[n * F_OUT + o] = mu;
    out_std[n * F_OUT + o] = sd;
    unsigned short h = f2bf(z);
    zhi[n * F_OUT + o] = h;
    zlo[n * F_OUT + o] = f2bf(z - bf2f(h));
}

// K7: adj = sigmoid(z @ z^T), split-bf16 (hi*hi + hi*lo + lo*hi), 64x64 per wave.
// XCD row-band swizzle (bid&7 -> band) for zhi/zlo L2 locality.
// NEW: epilogue restaged through 32 KB LDS half-tiles -> cooperative float4
// nontemporal stores, 1 KB contiguous per wave-instruction (vs 64 scalar dword
// stores at 2x128B segments). LDS does not cost occupancy (VGPR-bound ~3 blk/CU).
#define NT_TILES 157          // ceil(10000/64)
#define NT_CB    40           // col-blocks of 4 tiles (4 waves/block)
__global__ void __launch_bounds__(256) k7_adj(const unsigned short* __restrict__ zhi,
                                              const unsigned short* __restrict__ zlo,
                                              float* __restrict__ adj) {
    __shared__ float red[32 * 256];   // 32 KB: one 32-row half of the 64x256 block tile
    int bid = blockIdx.x;
    int xcd = bid & 7;
    int i = bid >> 3;
    int cb = i % NT_CB;
    int sti = xcd + 8 * (i / NT_CB);
    if (sti >= NT_TILES) return;

    int tid = threadIdx.x;
    int wid = tid >> 6, l = tid & 63;
    int stj = cb * 4 + wid;
    int stjc = min(stj, NT_TILES - 1);   // clamp; invalid cols predicated at store

    int rbase = sti * 64, cbase = stjc * 64;
    int half = l >> 5, lm = l & 31;
    int koff = half * 8;

    int ra0 = min(rbase + lm, N_NODES - 1);
    int ra1 = min(rbase + 32 + lm, N_NODES - 1);
    int rb0 = min(cbase + lm, N_NODES - 1);
    int rb1 = min(cbase + 32 + lm, N_NODES - 1);

    f32x16 acc[2][2];
    acc[0][0] = zero16(); acc[0][1] = zero16();
    acc[1][0] = zero16(); acc[1][1] = zero16();

#pragma unroll
    for (int c = 0; c < 4; ++c) {
        int ko = c * 16 + koff;
        bf16x8 ah[2], al[2], bh[2], bl[2];
        ah[0] = __builtin_bit_cast(bf16x8, *(const short8*)(zhi + (size_t)ra0 * 64 + ko));
        ah[1] = __builtin_bit_cast(bf16x8, *(const short8*)(zhi + (size_t)ra1 * 64 + ko));
        al[0] = __builtin_bit_cast(bf16x8, *(const short8*)(zlo + (size_t)ra0 * 64 + ko));
        al[1] = __builtin_bit_cast(bf16x8, *(const short8*)(zlo + (size_t)ra1 * 64 + ko));
        bh[0] = __builtin_bit_cast(bf16x8, *(const short8*)(zhi + (size_t)rb0 * 64 + ko));
        bh[1] = __builtin_bit_cast(bf16x8, *(const short8*)(zhi + (size_t)rb1 * 64 + ko));
        bl[0] = __builtin_bit_cast(bf16x8, *(const short8*)(zlo + (size_t)rb0 * 64 + ko));
        bl[1] = __builtin_bit_cast(bf16x8, *(const short8*)(zlo + (size_t)rb1 * 64 + ko));
#pragma unroll
        for (int rt = 0; rt < 2; ++rt)
#pragma unroll
            for (int ct = 0; ct < 2; ++ct) {
                acc[rt][ct] = __builtin_amdgcn_mfma_f32_32x32x16_bf16(ah[rt], bh[ct], acc[rt][ct], 0, 0, 0);
                acc[rt][ct] = __builtin_amdgcn_mfma_f32_32x32x16_bf16(ah[rt], bl[ct], acc[rt][ct], 0, 0, 0);
                acc[rt][ct] = __builtin_amdgcn_mfma_f32_32x32x16_bf16(al[rt], bh[ct], acc[rt][ct], 0, 0, 0);
            }
    }

    int colOrigin = cb * 256;            // block's global col origin (256 cols wide)
#pragma unroll
    for (int rt = 0; rt < 2; ++rt) {
        // sigmoid in registers -> LDS rows 0..31 of this half-tile
#pragma unroll
        for (int ct = 0; ct < 2; ++ct)
#pragma unroll
            for (int r = 0; r < 16; ++r) {
                int row = (r & 3) + 8 * (r >> 2) + 4 * half;      // 0..31
                int col = wid * 64 + ct * 32 + lm;                // 0..255
                float x = acc[rt][ct][r];
                float sig = __builtin_amdgcn_rcpf(1.f + __expf(-x));
                red[row * 256 + col] = sig;
            }
        __syncthreads();
        // cooperative coalesced store: each wave writes one full 1 KB row chunk
#pragma unroll
        for (int it = 0; it < 8; ++it) {
            int fid = it * 256 + tid;
            int row = fid >> 6;                 // uniform per wave
            int c4 = (fid & 63) * 4;
            int grow = rbase + rt * 32 + row;
            int gcol = colOrigin + c4;
            if (grow < N_NODES && gcol < N_NODES) {
                float4v v = *(const float4v*)&red[row * 256 + c4];
                __builtin_nontemporal_store(v, (float4v*)&adj[(size_t)grow * N_NODES + gcol]);
            }
        }
        __syncthreads();
    }
}

extern "C" void kernel_launch(void* const* d_in, const int* in_sizes, int n_in,
                              void* d_out, int out_size, void* d_ws, size_t ws_size,
                              hipStream_t stream) {
    const float* feat = (const float*)d_in[0];
    const float* eps  = (const float*)d_in[1];
    const int*   src  = (const int*)d_in[2];
    const int*   dst  = (const int*)d_in[3];
    const float* W1   = (const float*)d_in[4];
    const float* b1   = (const float*)d_in[5];
    const float* Wmu  = (const float*)d_in[6];
    const float* bmu  = (const float*)d_in[7];
    const float* Wstd = (const float*)d_in[8];
    const float* bstd = (const float*)d_in[9];

    float* out = (float*)d_out;
    float* adj     = out;
    float* out_mu  = out + 100000000;     // N*N
    float* out_std = out_mu + 640000;     // N*F_OUT

    float* h1p  = out + OFF_H1P;
    float* mup  = out + OFF_MUP;
    float* stdp = out + OFF_STDP;
    int* deg_in  = (int*)(out + OFF_DEGIN);
    int* deg_out = (int*)(out + OFF_DEGOUT);
    int* offs    = (int*)(out + OFF_OFFS);
    int* curs    = (int*)(out + OFF_CURS);
    float* sc_in  = out + OFF_SCIN;
    float* sc_out = out + OFF_SCOUT;
    int* csr = (int*)(out + OFF_CSR);
    unsigned short* wbuf = (unsigned short*)(out + OFF_WBUF);

    unsigned short* zhi = (unsigned short*)d_ws;
    unsigned short* zlo = zhi + 640000;

    // zero both degree arrays (contiguous 20000 ints)
    hipMemsetAsync(out + OFF_DEGIN, 0, 20000 * sizeof(int), stream);

    k0_deg_wswz<<<1378, 256, 0, stream>>>(src, dst, W1, deg_out, deg_in, wbuf);
    k1_scan<<<1, 1024, 0, stream>>>(deg_in, deg_out, offs, curs, sc_in, sc_out);
    k2_csr<<<1250, 256, 0, stream>>>(src, dst, curs, csr);
    k3_proj1<<<313, 256, 0, stream>>>(feat, wbuf, sc_out, h1p);
    k45_gather_proj<<<625, 1024, 0, stream>>>(offs, csr, h1p, sc_in, sc_out, b1,
                                              Wmu, Wstd, mup, stdp);
    k6_gather2<<<2500, 256, 0, stream>>>(offs, csr, mup, stdp, sc_in, bmu, bstd, eps,
                                         out_mu, out_std, zhi, zlo);
    k7_adj<<<8 * 20 * NT_CB, 256, 0, stream>>>(zhi, zlo, adj);
}

// Round 2
// 584.056 us; speedup vs baseline: 1.0820x; 1.0024x over previous
//
#include <hip/hip_runtime.h>
#include <stdint.h>

#define N_NODES 10000
#define N_EDGES 320000
#define F_IN 512
#define F_OUT 64

typedef __attribute__((ext_vector_type(8)))  __bf16 bf16x8;
typedef __attribute__((ext_vector_type(8)))  short  short8;
typedef __attribute__((ext_vector_type(16))) float  f32x16;
typedef __attribute__((ext_vector_type(4)))  float  float4v;

// ---- scratch layout inside d_out's adj region (float element offsets) ----
#define OFF_H1P    0          // 640,000 f
#define OFF_H1S    640000     // 640,000 f (h1 * sc_out, layer-2 gather input)
#define OFF_DEGIN  2560000    // 10,000 int
#define OFF_DEGOUT 2570000    // 10,000 int
#define OFF_OFFS   2580000    // 10,001 int
#define OFF_CURS   2592000    // 10,000 int
#define OFF_SCIN   2604000    // 10,000 f
#define OFF_SCOUT  2616000    // 10,000 f
#define OFF_CSR    2628000    // 320,000 int
#define OFF_WBUF   2948000    // 32,768 ushort (16,384 f), 16B-aligned

__device__ __forceinline__ unsigned short f2bf(float f) {
    unsigned u = __builtin_bit_cast(unsigned, f);
    u += 0x7fffu + ((u >> 16) & 1u);   // round-to-nearest-even
    return (unsigned short)(u >> 16);
}
__device__ __forceinline__ float bf2f(unsigned short h) {
    unsigned u = ((unsigned)h) << 16;
    return __builtin_bit_cast(float, u);
}
__device__ __forceinline__ f32x16 zero16() {
    f32x16 v;
#pragma unroll
    for (int i = 0; i < 16; ++i) v[i] = 0.f;
    return v;
}

// K0: integer degrees via atomics + swizzle W1 into MFMA B-fragment-linear bf16
__global__ void k0_deg_wswz(const int* __restrict__ src, const int* __restrict__ dst,
                            const float* __restrict__ W1,
                            int* __restrict__ deg_out, int* __restrict__ deg_in,
                            unsigned short* __restrict__ wbuf) {
    int bid = blockIdx.x, tid = threadIdx.x;
    if (bid < 1250) {
        int e = bid * 256 + tid;
        if (e < N_EDGES) {
            atomicAdd(&deg_out[src[e]], 1);
            atomicAdd(&deg_in[dst[e]], 1);
        }
    } else {
        int q = (bid - 1250) * 256 + tid;   // 2*32*64*8 = 32768 exactly
        int j = q & 7, l = (q >> 3) & 63, c = (q >> 9) & 31, t = q >> 14;
        int k = c * 16 + ((l >> 5) << 3) + j;        // B frag: k = c*16 + half*8 + j
        int n = (t << 5) + (l & 31);                 // n = tile*32 + (lane&31)
        wbuf[q] = f2bf(W1[k * F_OUT + n]);
    }
}

// K1: single-block exclusive scan of deg_in -> CSR offsets + cursors + rsqrt scales
__global__ void __launch_bounds__(1024) k1_scan(const int* __restrict__ deg_in,
                                                const int* __restrict__ deg_out,
                                                int* __restrict__ offs, int* __restrict__ curs,
                                                float* __restrict__ sc_in, float* __restrict__ sc_out) {
    __shared__ int sdata[1024];
    int t = threadIdx.x;
    int loc[10];
    int s = 0;
#pragma unroll
    for (int u = 0; u < 10; ++u) {
        int idx = t * 10 + u;
        int v = (idx < N_NODES) ? deg_in[idx] : 0;
        loc[u] = v; s += v;
    }
    sdata[t] = s;
    __syncthreads();
    for (int off = 1; off < 1024; off <<= 1) {
        int v = sdata[t];
        int add = (t >= off) ? sdata[t - off] : 0;
        __syncthreads();
        sdata[t] = v + add;
        __syncthreads();
    }
    int run = (t == 0) ? 0 : sdata[t - 1];
#pragma unroll
    for (int u = 0; u < 10; ++u) {
        int idx = t * 10 + u;
        if (idx < N_NODES) {
            offs[idx] = run; curs[idx] = run;
            run += loc[u];
            sc_in[idx] = rsqrtf((float)max(loc[u], 1));
            sc_out[idx] = rsqrtf((float)max(deg_out[idx], 1));
        }
    }
    if (t == 1023) offs[N_NODES] = sdata[1023];
}

// K2: CSR fill (edge list bucketed by dst)
__global__ void k2_csr(const int* __restrict__ src, const int* __restrict__ dst,
                       int* __restrict__ curs, int* __restrict__ csr) {
    int e = blockIdx.x * 256 + threadIdx.x;
    if (e < N_EDGES) {
        int d = dst[e];
        int p = atomicAdd(&curs[d], 1);
        csr[p] = src[e];
    }
}

// K3: h1p = (feat @ W1) * rsqrt(deg_out)  via bf16 MFMA, split-K over 4 waves
__global__ void __launch_bounds__(256) k3_proj1(const float* __restrict__ feat,
                                                const unsigned short* __restrict__ wbuf,
                                                const float* __restrict__ sc_out,
                                                float* __restrict__ h1p) {
    __shared__ float red[4][32 * 64];  // 32 KB
    int tid = threadIdx.x;
    int wid = tid >> 6;
    int l = tid & 63;
    int half = l >> 5;
    int rowbase = blockIdx.x * 32;
    int m = rowbase + (l & 31);
    if (m > N_NODES - 1) m = N_NODES - 1;
    const float* arow = feat + (size_t)m * F_IN + half * 8;

    f32x16 acc0 = zero16(), acc1 = zero16();
    int cbeg = wid * 8;
#pragma unroll
    for (int cc = 0; cc < 8; ++cc) {
        int c = cbeg + cc;
        float4v a0 = *(const float4v*)(arow + c * 16);
        float4v a1 = *(const float4v*)(arow + c * 16 + 4);
        short8 as;
        as[0] = (short)f2bf(a0[0]); as[1] = (short)f2bf(a0[1]);
        as[2] = (short)f2bf(a0[2]); as[3] = (short)f2bf(a0[3]);
        as[4] = (short)f2bf(a1[0]); as[5] = (short)f2bf(a1[1]);
        as[6] = (short)f2bf(a1[2]); as[7] = (short)f2bf(a1[3]);
        bf16x8 af = __builtin_bit_cast(bf16x8, as);
        bf16x8 b0 = __builtin_bit_cast(bf16x8, *(const short8*)(wbuf + (size_t)((0 * 32 + c) * 64 + l) * 8));
        bf16x8 b1 = __builtin_bit_cast(bf16x8, *(const short8*)(wbuf + (size_t)((1 * 32 + c) * 64 + l) * 8));
        acc0 = __builtin_amdgcn_mfma_f32_32x32x16_bf16(af, b0, acc0, 0, 0, 0);
        acc1 = __builtin_amdgcn_mfma_f32_32x32x16_bf16(af, b1, acc1, 0, 0, 0);
    }
#pragma unroll
    for (int r = 0; r < 16; ++r) {
        int row = (r & 3) + 8 * (r >> 2) + 4 * half;   // 32x32 C/D layout
        int col = l & 31;
        red[wid][row * 64 + col] = acc0[r];
        red[wid][row * 64 + 32 + col] = acc1[r];
    }
    __syncthreads();
#pragma unroll
    for (int i = 0; i < 8; ++i) {
        int idx = tid * 8 + i;
        int row = idx >> 6, col = idx & 63;
        int gr = rowbase + row;
        if (gr < N_NODES) {
            float v = red[0][idx] + red[1][idx] + red[2][idx] + red[3][idx];
            h1p[gr * F_OUT + col] = v * sc_out[gr];
        }
    }
}

// K4: h1s[n] = (rsqrt(deg_in[n]) * sum_{e in(n)} h1p[src] + b1) * rsqrt(deg_out[n])
// (h1 never materialized separately; sc_out folded in so layer 2 becomes
//  gather-then-project: sum_e (h1s@W) == (sum_e h1s)@W, linearity.)
// Gather unrolled x4: 4 independent csr loads then 4 independent row loads
// per round -> breaks the dependent L2-latency chain.
__global__ void __launch_bounds__(256) k4_gather1(const int* __restrict__ offs, const int* __restrict__ csr,
                                                  const float* __restrict__ h1p,
                                                  const float* __restrict__ sc_in, const float* __restrict__ sc_out,
                                                  const float* __restrict__ b1, float* __restrict__ h1s) {
    int tid = threadIdx.x;
    int n = blockIdx.x * 4 + (tid >> 6);   // grid=2500 exact
    int o = tid & 63;
    int e0 = offs[n], e1 = offs[n + 1];
    float acc = 0.f;
    int e = e0;
    for (; e + 4 <= e1; e += 4) {
        int s0 = csr[e], s1 = csr[e + 1], s2 = csr[e + 2], s3 = csr[e + 3];
        float v0 = h1p[s0 * F_OUT + o];
        float v1 = h1p[s1 * F_OUT + o];
        float v2 = h1p[s2 * F_OUT + o];
        float v3 = h1p[s3 * F_OUT + o];
        acc += v0; acc += v1; acc += v2; acc += v3;
    }
    for (; e < e1; ++e) acc += h1p[csr[e] * F_OUT + o];
    h1s[n * F_OUT + o] = (acc * sc_in[n] + b1[o]) * sc_out[n];
}

// K6: g = gather(h1s) over in-edges (ONE gather instead of two);
//     mu = sc_in*(g@Wmu)+bmu; lv = sc_in*(g@Wstd)+bstd; std=exp(lv);
//     z = eps*std + mu; emit z_hi/z_lo bf16 split + mu/std outputs (NT stores).
__global__ void __launch_bounds__(1024) k6_gather_proj(
        const int* __restrict__ offs, const int* __restrict__ csr,
        const float* __restrict__ h1s, const float* __restrict__ sc_in,
        const float* __restrict__ Wmu, const float* __restrict__ Wstd,
        const float* __restrict__ bmu, const float* __restrict__ bstd,
        const float* __restrict__ eps,
        float* __restrict__ out_mu, float* __restrict__ out_std,
        unsigned short* __restrict__ zhi, unsigned short* __restrict__ zlo) {
    __shared__ float wmuT[64 * 65];   // +1 pad: bank-conflict-free
    __shared__ float wstdT[64 * 65];
    __shared__ float grow[16 * 64];
    int tid = threadIdx.x;
#pragma unroll
    for (int i0 = 0; i0 < 4096; i0 += 1024) {
        int i = i0 + tid;
        int k = i >> 6, o2 = i & 63;
        wmuT[o2 * 65 + k] = Wmu[i];
        wstdT[o2 * 65 + k] = Wstd[i];
    }
    int ln = tid >> 6, o = tid & 63;
    int n = blockIdx.x * 16 + ln;      // grid=625 exact
    int e0 = offs[n], e1 = offs[n + 1];
    float acc = 0.f;
    int e = e0;
    for (; e + 4 <= e1; e += 4) {
        int s0 = csr[e], s1 = csr[e + 1], s2 = csr[e + 2], s3 = csr[e + 3];
        float v0 = h1s[s0 * F_OUT + o];
        float v1 = h1s[s1 * F_OUT + o];
        float v2 = h1s[s2 * F_OUT + o];
        float v3 = h1s[s3 * F_OUT + o];
        acc += v0; acc += v1; acc += v2; acc += v3;
    }
    for (; e < e1; ++e) acc += h1s[csr[e] * F_OUT + o];
    grow[ln * 64 + o] = acc;
    __syncthreads();   // covers W staging + grow
    float amu = 0.f, asd = 0.f;
#pragma unroll
    for (int k = 0; k < 64; ++k) {
        float g = grow[ln * 64 + k];
        amu += g * wmuT[o * 65 + k];
        asd += g * wstdT[o * 65 + k];
    }
    float si = sc_in[n];
    float mu = amu * si + bmu[o];
    float lv = asd * si + bstd[o];
    float sd = __expf(lv);
    float z = eps[n * F_OUT + o] * sd + mu;
    __builtin_nontemporal_store(mu, &out_mu[n * F_OUT + o]);   // final outputs: keep L2 for zhi/zlo
    __builtin_nontemporal_store(sd, &out_std[n * F_OUT + o]);
    unsigned short h = f2bf(z);
    zhi[n * F_OUT + o] = h;
    zlo[n * F_OUT + o] = f2bf(z - bf2f(h));
}

// K7: adj = sigmoid(z @ z^T), split-bf16 (hi*hi + hi*lo + lo*hi), 64x64 per wave.
// XCD row-band swizzle (bid&7 -> band) for zhi/zlo L2 locality.
// Epilogue: per-wave PRIVATE 8KB LDS slice -> float4 NT stores (256B-aligned
// chunks). Wave-local ds RAW is ordered by lgkmcnt; ZERO __syncthreads, so
// waves drain their store queues independently (no lockstep vs HBM drain).
#define NT_TILES 157          // ceil(10000/64)
#define NT_CB    40           // col-blocks of 4 tiles (4 waves/block)
__global__ void __launch_bounds__(256) k7_adj(const unsigned short* __restrict__ zhi,
                                              const unsigned short* __restrict__ zlo,
                                              float* __restrict__ adj) {
    __shared__ float red[4][32 * 64];   // 32 KB total, 8 KB per wave
    int bid = blockIdx.x;
    int xcd = bid & 7;
    int i = bid >> 3;
    int cb = i % NT_CB;
    int sti = xcd + 8 * (i / NT_CB);
    if (sti >= NT_TILES) return;

    int tid = threadIdx.x;
    int wid = tid >> 6, l = tid & 63;
    int stj = cb * 4 + wid;
    int stjc = min(stj, NT_TILES - 1);   // clamp; OOB cols predicated at store

    int rbase = sti * 64, cbase = stjc * 64;
    int half = l >> 5, lm = l & 31;
    int koff = half * 8;

    int ra0 = min(rbase + lm, N_NODES - 1);
    int ra1 = min(rbase + 32 + lm, N_NODES - 1);
    int rb0 = min(cbase + lm, N_NODES - 1);
    int rb1 = min(cbase + 32 + lm, N_NODES - 1);

    f32x16 acc[2][2];
    acc[0][0] = zero16(); acc[0][1] = zero16();
    acc[1][0] = zero16(); acc[1][1] = zero16();

#pragma unroll
    for (int c = 0; c < 4; ++c) {
        int ko = c * 16 + koff;
        bf16x8 ah[2], al[2], bh[2], bl[2];
        ah[0] = __builtin_bit_cast(bf16x8, *(const short8*)(zhi + (size_t)ra0 * 64 + ko));
        ah[1] = __builtin_bit_cast(bf16x8, *(const short8*)(zhi + (size_t)ra1 * 64 + ko));
        al[0] = __builtin_bit_cast(bf16x8, *(const short8*)(zlo + (size_t)ra0 * 64 + ko));
        al[1] = __builtin_bit_cast(bf16x8, *(const short8*)(zlo + (size_t)ra1 * 64 + ko));
        bh[0] = __builtin_bit_cast(bf16x8, *(const short8*)(zhi + (size_t)rb0 * 64 + ko));
        bh[1] = __builtin_bit_cast(bf16x8, *(const short8*)(zhi + (size_t)rb1 * 64 + ko));
        bl[0] = __builtin_bit_cast(bf16x8, *(const short8*)(zlo + (size_t)rb0 * 64 + ko));
        bl[1] = __builtin_bit_cast(bf16x8, *(const short8*)(zlo + (size_t)rb1 * 64 + ko));
#pragma unroll
        for (int rt = 0; rt < 2; ++rt)
#pragma unroll
            for (int ct = 0; ct < 2; ++ct) {
                acc[rt][ct] = __builtin_amdgcn_mfma_f32_32x32x16_bf16(ah[rt], bh[ct], acc[rt][ct], 0, 0, 0);
                acc[rt][ct] = __builtin_amdgcn_mfma_f32_32x32x16_bf16(ah[rt], bl[ct], acc[rt][ct], 0, 0, 0);
                acc[rt][ct] = __builtin_amdgcn_mfma_f32_32x32x16_bf16(al[rt], bh[ct], acc[rt][ct], 0, 0, 0);
            }
    }

    int colw = cb * 256 + wid * 64;      // this wave's global col origin
#pragma unroll
    for (int rt = 0; rt < 2; ++rt) {
        // sigmoid in registers -> this wave's private LDS slice (32 rows x 64 cols)
#pragma unroll
        for (int ct = 0; ct < 2; ++ct)
#pragma unroll
            for (int r = 0; r < 16; ++r) {
                int row = (r & 3) + 8 * (r >> 2) + 4 * half;      // 0..31
                int col = ct * 32 + lm;                           // 0..63
                float x = acc[rt][ct][r];
                red[wid][row * 64 + col] = __builtin_amdgcn_rcpf(1.f + __expf(-x));
            }
        // wave-local readback: 8 x float4 NT stores, 4 rows x 256B per instr
#pragma unroll
        for (int it = 0; it < 8; ++it) {
            int row4 = it * 4 + (l >> 4);
            int c4 = (l & 15) * 4;
            int grow = rbase + rt * 32 + row4;
            int gcol = colw + c4;
            if (grow < N_NODES && gcol < N_NODES) {
                float4v v = *(const float4v*)&red[wid][row4 * 64 + c4];
                __builtin_nontemporal_store(v, (float4v*)&adj[(size_t)grow * N_NODES + gcol]);
            }
        }
    }
}

extern "C" void kernel_launch(void* const* d_in, const int* in_sizes, int n_in,
                              void* d_out, int out_size, void* d_ws, size_t ws_size,
                              hipStream_t stream) {
    const float* feat = (const float*)d_in[0];
    const float* eps  = (const float*)d_in[1];
    const int*   src  = (const int*)d_in[2];
    const int*   dst  = (const int*)d_in[3];
    const float* W1   = (const float*)d_in[4];
    const float* b1   = (const float*)d_in[5];
    const float* Wmu  = (const float*)d_in[6];
    const float* bmu  = (const float*)d_in[7];
    const float* Wstd = (const float*)d_in[8];
    const float* bstd = (const float*)d_in[9];

    float* out = (float*)d_out;
    float* adj     = out;
    float* out_mu  = out + 100000000;     // N*N
    float* out_std = out_mu + 640000;     // N*F_OUT

    float* h1p  = out + OFF_H1P;
    float* h1s  = out + OFF_H1S;
    int* deg_in  = (int*)(out + OFF_DEGIN);
    int* deg_out = (int*)(out + OFF_DEGOUT);
    int* offs    = (int*)(out + OFF_OFFS);
    int* curs    = (int*)(out + OFF_CURS);
    float* sc_in  = out + OFF_SCIN;
    float* sc_out = out + OFF_SCOUT;
    int* csr = (int*)(out + OFF_CSR);
    unsigned short* wbuf = (unsigned short*)(out + OFF_WBUF);

    unsigned short* zhi = (unsigned short*)d_ws;
    unsigned short* zlo = zhi + 640000;

    // zero both degree arrays (contiguous 20000 ints)
    hipMemsetAsync(out + OFF_DEGIN, 0, 20000 * sizeof(int), stream);

    k0_deg_wswz<<<1378, 256, 0, stream>>>(src, dst, W1, deg_out, deg_in, wbuf);
    k1_scan<<<1, 1024, 0, stream>>>(deg_in, deg_out, offs, curs, sc_in, sc_out);
    k2_csr<<<1250, 256, 0, stream>>>(src, dst, curs, csr);
    k3_proj1<<<313, 256, 0, stream>>>(feat, wbuf, sc_out, h1p);
    k4_gather1<<<2500, 256, 0, stream>>>(offs, csr, h1p, sc_in, sc_out, b1, h1s);
    k6_gather_proj<<<625, 1024, 0, stream>>>(offs, csr, h1s, sc_in, Wmu, Wstd,
                                             bmu, bstd, eps, out_mu, out_std, zhi, zlo);
    k7_adj<<<8 * 20 * NT_CB, 256, 0, stream>>>(zhi, zlo, adj);
}